// Round 1
// baseline (73.642 us; speedup 1.0000x reference)
//
#include <hip/hip_runtime.h>

// SeparationLoss: landmarks [B=1024, N=256, D=2] fp32 -> scalar fp32
//   sum_{b} sum_{i<j} d2 * exp(-d2/25),  d2 = ||x_i - x_j||^2
// Strategy: full NxN symmetric sum (diagonal contributes 0) * 0.5 -> uniform
// loop, no divergence. One block per batch; points staged in LDS; per-thread
// register accumulate; wave shuffle reduce; one atomicAdd per block.

#define N_PTS 256
#define INV_SIGMA2 (1.0f / 25.0f)

__global__ void sep_init(float* out) { out[0] = 0.0f; }

__global__ __launch_bounds__(256) void sep_loss_kernel(
    const float* __restrict__ lm, float* __restrict__ out) {
    __shared__ float2 pts[N_PTS];
    const int b = blockIdx.x;
    const int t = threadIdx.x;

    // coalesced load: 256 threads x 8B = one batch's points
    const float2* src = (const float2*)(lm + (size_t)b * N_PTS * 2);
    pts[t] = src[t];
    __syncthreads();

    const float xi = pts[t].x;
    const float yi = pts[t].y;

    float s = 0.0f;
#pragma unroll 8
    for (int j = 0; j < N_PTS; ++j) {
        // all lanes read the same LDS address -> broadcast, conflict-free
        float dx = xi - pts[j].x;
        float dy = yi - pts[j].y;
        float d2 = dx * dx + dy * dy;          // >= 0 by construction
        s += d2 * __expf(-d2 * INV_SIGMA2);    // i==j term is exactly 0
    }

    // wave (64-lane) butterfly reduce
    for (int off = 32; off > 0; off >>= 1) s += __shfl_down(s, off, 64);

    __shared__ float wsum[4];
    if ((t & 63) == 0) wsum[t >> 6] = s;
    __syncthreads();

    if (t == 0) {
        float tot = wsum[0] + wsum[1] + wsum[2] + wsum[3];
        atomicAdd(out, 0.5f * tot);  // 0.5: full-matrix -> upper triangle
    }
}

extern "C" void kernel_launch(void* const* d_in, const int* in_sizes, int n_in,
                              void* d_out, int out_size, void* d_ws, size_t ws_size,
                              hipStream_t stream) {
    const float* landmarks = (const float*)d_in[0];
    float* out = (float*)d_out;

    const int B = in_sizes[0] / (N_PTS * 2);  // 1024

    sep_init<<<1, 1, 0, stream>>>(out);
    sep_loss_kernel<<<B, N_PTS, 0, stream>>>(landmarks, out);
}

// Round 2
// 61.759 us; speedup vs baseline: 1.1924x; 1.1924x over previous
//
#include <hip/hip_runtime.h>

// SeparationLoss: landmarks [B=1024, N=256, D=2] fp32 -> scalar fp32
//   sum_b sum_{i<j} d2 * exp(-d2/25),  d2 = ||x_i - x_j||^2
//
// Circular pairing: thread i pairs with (i+j) mod 256 for j=1..127 (each
// unordered pair exactly once) + half-weight j=128 (each pair hit twice).
// Uniform 128-iter loop, no divergence, half the work of full NxN.
// Points duplicated in LDS so (i+j) needs no modulo -> imm-offset ds_read_b64,
// stride-8B across lanes = 2-way bank alias = free (m136).
// exp(-d2/25) = exp2(C*d2), C = -log2(e)/25 -> guaranteed single v_exp_f32.
// 4 accumulators break the strict-FP serial add chain.
// Block partials -> d_ws, then a 1-block reduce (no same-address atomics).

#define N_PTS 256
#define EXP2_C (-0.057707801635558534f)  // -log2(e)/25

__device__ __forceinline__ float fast_exp2(float x) {
#if __has_builtin(__builtin_amdgcn_exp2f)
    return __builtin_amdgcn_exp2f(x);
#else
    return exp2f(x);
#endif
}

__global__ __launch_bounds__(256) void sep_main(
    const float* __restrict__ lm, float* __restrict__ partial) {
    __shared__ float2 pts[2 * N_PTS];
    const int b = blockIdx.x;
    const int t = threadIdx.x;

    const float2* src = (const float2*)(lm + (size_t)b * N_PTS * 2);
    float2 p = src[t];          // coalesced 8B/lane
    pts[t] = p;
    pts[t + N_PTS] = p;         // duplicate: kills the modulo
    __syncthreads();

    const float xi = p.x, yi = p.y;
    const float2* row = &pts[t];

    float s0 = 0.f, s1 = 0.f, s2 = 0.f, s3 = 0.f;
#pragma unroll 4
    for (int j = 1; j <= 125; j += 4) {
        float2 q0 = row[j];
        float2 q1 = row[j + 1];
        float2 q2 = row[j + 2];
        float2 q3 = row[j + 3];
        float dx, dy, d2;
        dx = xi - q0.x; dy = yi - q0.y; d2 = dx * dx + dy * dy;
        s0 += d2 * fast_exp2(EXP2_C * d2);
        dx = xi - q1.x; dy = yi - q1.y; d2 = dx * dx + dy * dy;
        s1 += d2 * fast_exp2(EXP2_C * d2);
        dx = xi - q2.x; dy = yi - q2.y; d2 = dx * dx + dy * dy;
        s2 += d2 * fast_exp2(EXP2_C * d2);
        dx = xi - q3.x; dy = yi - q3.y; d2 = dx * dx + dy * dy;
        s3 += d2 * fast_exp2(EXP2_C * d2);
    }
    // offset 128: each unordered pair generated twice -> half weight
    {
        float2 q = row[N_PTS / 2];
        float dx = xi - q.x, dy = yi - q.y;
        float d2 = dx * dx + dy * dy;
        s0 += 0.5f * d2 * fast_exp2(EXP2_C * d2);
    }

    float s = (s0 + s1) + (s2 + s3);

    // wave butterfly reduce (64 lanes)
    for (int off = 32; off > 0; off >>= 1) s += __shfl_down(s, off, 64);

    __shared__ float wsum[4];
    if ((t & 63) == 0) wsum[t >> 6] = s;
    __syncthreads();
    if (t == 0) partial[b] = (wsum[0] + wsum[1]) + (wsum[2] + wsum[3]);
}

__global__ __launch_bounds__(256) void sep_reduce(
    const float* __restrict__ partial, float* __restrict__ out) {
    const int t = threadIdx.x;
    const float4* p4 = (const float4*)partial;   // 256 threads x 4 = 1024
    float4 v = p4[t];
    float s = (v.x + v.y) + (v.z + v.w);
    for (int off = 32; off > 0; off >>= 1) s += __shfl_down(s, off, 64);
    __shared__ float wsum[4];
    if ((t & 63) == 0) wsum[t >> 6] = s;
    __syncthreads();
    if (t == 0) out[0] = (wsum[0] + wsum[1]) + (wsum[2] + wsum[3]);
}

extern "C" void kernel_launch(void* const* d_in, const int* in_sizes, int n_in,
                              void* d_out, int out_size, void* d_ws, size_t ws_size,
                              hipStream_t stream) {
    const float* landmarks = (const float*)d_in[0];
    float* out = (float*)d_out;
    float* partial = (float*)d_ws;               // 1024 floats = 4 KB

    const int B = in_sizes[0] / (N_PTS * 2);     // 1024

    sep_main<<<B, N_PTS, 0, stream>>>(landmarks, partial);
    sep_reduce<<<1, N_PTS, 0, stream>>>(partial, out);
}